// Round 1
// baseline (113.403 us; speedup 1.0000x reference)
//
#include <hip/hip_runtime.h>
#include <math.h>

namespace {

constexpr int K_   = 9;
constexpr int NC_  = 13;
constexpr int NA_  = 5;
constexpr int NL_  = 21;      // 2K+3
constexpr int NB_  = 32;
constexpr int NH_  = 32;
constexpr int NW_  = 32;
constexpr int NPIX = NH_ * NW_;     // 1024
constexpr int M_   = NA_ * NPIX;    // 5120
constexpr int N_   = NB_ * M_;      // 163840
constexpr int NT_  = 50;
constexpr int CH_  = 2 * K_ + 1 + NC_;  // 32 channels per anchor
constexpr int SUBS = M_ / 256;      // 20 blocks per batch in k_cells

constexpr float TH_    = 30.0f;
constexpr float SHARP_ = 2.0f;
constexpr float IMW_   = 640.0f;
constexpr float IMH_   = 480.0f;
constexpr float EPS_   = 1e-5f;
constexpr float SIL_   = 0.6f;
constexpr float OBJ_   = 5.0f;

__device__ __constant__ float c_aw[5] = {1.482f, 2.0501f, 2.3946f, 3.1018f, 3.4879f};
__device__ __constant__ float c_ah[5] = {2.2412f, 3.1265f, 4.6891f, 3.991f, 5.2505f};

__device__ __forceinline__ float sigm(float x) { return 1.0f / (1.0f + expf(-x)); }

// ---------------- Kernel 1: per-target bookkeeping (1600 targets) -------------
__global__ void k_targets(const float* __restrict__ outp,
                          const float* __restrict__ tgt,
                          int*   __restrict__ tmap,
                          float* __restrict__ t_conf,
                          float* __restrict__ t_txs,
                          float* __restrict__ t_tys,
                          int*   __restrict__ t_cls)
{
    int idx = blockIdx.x * blockDim.x + threadIdx.x;
    if (idx >= NB_ * NT_) return;
    int b = idx / NT_, t = idx - b * NT_;
    const float* tb  = tgt + (size_t)b * NT_ * NL_;
    const float* row = tb + t * NL_;

    // valid = cumprod over t of (first-kp-x != 0)
    bool valid = true;
    for (int tp = 0; tp <= t; ++tp)
        if (tb[tp * NL_ + 1] == 0.0f) { valid = false; break; }

    float gxn[K_], gyn[K_];
#pragma unroll
    for (int k = 0; k < K_; ++k) { gxn[k] = row[1 + 2 * k]; gyn[k] = row[2 + 2 * k]; }

    int gi0 = (int)(gxn[0] * (float)NW_);
    int gj0 = (int)(gyn[0] * (float)NH_);
    float gw = row[NL_ - 2] * (float)NW_;
    float gh = row[NL_ - 1] * (float)NH_;

    // best anchor by IoU (first-max, -1 if max<=0)
    float best_iou = 0.0f; int best_n = -1;
#pragma unroll
    for (int a = 0; a < NA_; ++a) {
        float cw  = fminf(c_aw[a], gw);
        float chh = fminf(c_ah[a], gh);
        float iou = 0.0f;
        if (cw > 0.0f && chh > 0.0f) {
            float inter = cw * chh;
            iou = inter / (c_aw[a] * c_ah[a] + gw * gh - inter);
        }
        if (iou > best_iou) { best_iou = iou; best_n = a; }
    }
    int bn = ((best_n % NA_) + NA_) % NA_;   // Python -1 % 5 == 4
    int flat = ((b * NA_ + bn) * NH_ + gj0) * NW_ + gi0;

#pragma unroll
    for (int k = 0; k < K_; ++k) {
        t_txs[idx * K_ + k] = gxn[k] * (float)NW_ - (float)gi0;
        t_tys[idx * K_ + k] = gyn[k] * (float)NH_ - (float)gj0;
    }
    t_cls[idx] = (int)row[0];

    // conf_t: corner-conf against prediction at cell pb = (b*M - nPix + gj0*nW + gi0) mod N
    long long pbl = (long long)b * M_ - NPIX + gj0 * NW_ + gi0;
    int pb = (int)(((pbl % N_) + N_) % N_);
    int b2 = pb / M_;   int m2   = pb - b2 * M_;
    int a2 = m2 / NPIX; int pix2 = m2 - a2 * NPIX;
    int h2 = pix2 / NW_; int w2 = pix2 - h2 * NW_;
    const float* cb = outp + ((size_t)(b2 * NA_ + a2)) * CH_ * NPIX + pix2;

    float xsv[K_], ysv[K_];
    xsv[0] = sigm(cb[0]);
    ysv[0] = sigm(cb[NPIX]);
#pragma unroll
    for (int k = 1; k < K_; ++k) {
        xsv[k] = cb[(size_t)(k + 2) * NPIX];   // channels 3..10
        ysv[k] = cb[(size_t)(k + 3) * NPIX];   // channels 4..11 (overlap is intentional)
    }
    float s = 0.0f;
#pragma unroll
    for (int k = 0; k < K_; ++k) {
        float px = (xsv[k] + (float)w2) * (1.0f / NW_);
        float py = (ysv[k] + (float)h2) * (1.0f / NH_);
        float dx = (gxn[k] - px) * IMW_;
        float dy = (gyn[k] - py) * IMH_;
        float d2 = dx * dx + dy * dy;
        if (d2 < TH_ * TH_)
            s += expf(SHARP_ * (1.0f - sqrtf(d2) * (1.0f / TH_))) - 1.0f;
    }
    t_conf[idx] = s * (1.0f / ((expf(SHARP_) - 1.0f + EPS_) * (float)K_));

    if (valid) atomicMax(&tmap[flat], t + 1);   // scatter-max: order-independent
}

// ---------------- Kernel 2: per-cell losses (N cells) -------------------------
__global__ __launch_bounds__(256) void k_cells(
        const float* __restrict__ outp,
        const float* __restrict__ tgt,
        const int*   __restrict__ tmap,
        const float* __restrict__ t_conf,
        const float* __restrict__ t_txs,
        const float* __restrict__ t_tys,
        const int*   __restrict__ t_cls,
        float* __restrict__ partial)
{
    __shared__ float s_gx[NT_ * K_];
    __shared__ float s_gy[NT_ * K_];
    __shared__ int   s_nv;
    __shared__ float s_red[8];

    int b   = blockIdx.x / SUBS;
    int sub = blockIdx.x - b * SUBS;
    int tid = threadIdx.x;

    const float* tb = tgt + (size_t)b * NT_ * NL_;
    for (int i = tid; i < NT_ * K_; i += 256) {
        int t = i / K_, k = i - t * K_;
        s_gx[i] = tb[t * NL_ + 1 + 2 * k] * IMW_;   // pre-scaled to pixels
        s_gy[i] = tb[t * NL_ + 2 + 2 * k] * IMH_;
    }
    if (tid == 0) {
        int nv = 0;
        while (nv < NT_ && tb[nv * NL_ + 1] != 0.0f) nv++;
        s_nv = nv;
    }
    __syncthreads();

    int m = sub * 256 + tid;
    int n = b * M_ + m;
    int a = m / NPIX;  int pix = m - a * NPIX;
    int h = pix / NW_; int w   = pix - h * NW_;
    const float* cb = outp + ((size_t)(b * NA_ + a)) * CH_ * NPIX + pix;

    float xsv[K_], ysv[K_], pxs[K_], pys[K_];
    xsv[0] = sigm(cb[0]);
    ysv[0] = sigm(cb[NPIX]);
#pragma unroll
    for (int k = 1; k < K_; ++k) {
        xsv[k] = cb[(size_t)(k + 2) * NPIX];
        ysv[k] = cb[(size_t)(k + 3) * NPIX];
    }
#pragma unroll
    for (int k = 0; k < K_; ++k) {
        pxs[k] = (xsv[k] + (float)w) * (IMW_ / NW_);   // px * IMW
        pys[k] = (ysv[k] + (float)h) * (IMH_ / NH_);   // py * IMH
    }

    // cur = max over valid targets of mean-k corner conf (scale applied after max)
    int nv = s_nv;
    float cur = 0.0f;
    for (int t = 0; t < nv; ++t) {
        float s = 0.0f;
#pragma unroll
        for (int k = 0; k < K_; ++k) {
            float dx = s_gx[t * K_ + k] - pxs[k];
            float dy = s_gy[t * K_ + k] - pys[k];
            float d2 = fmaf(dx, dx, dy * dy);
            if (d2 < TH_ * TH_)
                s += expf(SHARP_ - (SHARP_ / TH_) * sqrtf(d2)) - 1.0f;
        }
        cur = fmaxf(cur, s);
    }
    cur *= 1.0f / ((expf(SHARP_) - 1.0f + EPS_) * (float)K_);
    float cm0 = (cur > SIL_) ? 0.0f : 1.0f;    // NOOBJ=1

    int tm = tmap[n];
    float cf = sigm(cb[(size_t)(2 * K_) * NPIX]);   // channel 18
    float acc_main = 0.0f, acc_conf = 0.0f;
    if (tm > 0) {
        int widx = b * NT_ + (tm - 1);
        float lxy = 0.0f;
#pragma unroll
        for (int k = 0; k < K_; ++k) {
            float ddx = xsv[k] - t_txs[widx * K_ + k];
            float ddy = ysv[k] - t_tys[widx * K_ + k];
            lxy += ddx * ddx + ddy * ddy;
        }
        float diff = cf - t_conf[widx];
        acc_conf = 0.5f * OBJ_ * diff * diff;

        float logits[NC_]; float mx = -1e30f;
#pragma unroll
        for (int c = 0; c < NC_; ++c) {
            logits[c] = cb[(size_t)(2 * K_ + 1 + c) * NPIX];
            mx = fmaxf(mx, logits[c]);
        }
        float se = 0.0f;
#pragma unroll
        for (int c = 0; c < NC_; ++c) se += expf(logits[c] - mx);
        int ci = t_cls[widx];
        ci = ci < 0 ? 0 : (ci > NC_ - 1 ? NC_ - 1 : ci);   // JAX gather clamps
        acc_main = 0.5f * lxy + (mx + logf(se) - logits[ci]);
    } else {
        acc_conf = 0.5f * cf * cf * cm0;
    }

    // deterministic block reduction
    float v0 = acc_main, v1 = acc_conf;
#pragma unroll
    for (int off = 32; off > 0; off >>= 1) {
        v0 += __shfl_down(v0, off);
        v1 += __shfl_down(v1, off);
    }
    int lane = tid & 63, wv = tid >> 6;
    if (lane == 0) { s_red[wv] = v0; s_red[4 + wv] = v1; }
    __syncthreads();
    if (tid == 0) {
        float a0 = 0.0f, a1 = 0.0f;
        for (int i = 0; i < 4; ++i) { a0 += s_red[i]; a1 += s_red[4 + i]; }
        partial[blockIdx.x * 2]     = a0;
        partial[blockIdx.x * 2 + 1] = a1;
    }
}

// ---------------- Kernel 3: final reduction + epoch gate ----------------------
__global__ __launch_bounds__(256) void k_final(const float* __restrict__ partial,
                                               const int* __restrict__ epoch,
                                               float* __restrict__ outp)
{
    __shared__ float s_red[8];
    int tid = threadIdx.x;
    float v0 = 0.0f, v1 = 0.0f;
    for (int i = tid; i < NB_ * SUBS; i += 256) {
        v0 += partial[2 * i];
        v1 += partial[2 * i + 1];
    }
#pragma unroll
    for (int off = 32; off > 0; off >>= 1) {
        v0 += __shfl_down(v0, off);
        v1 += __shfl_down(v1, off);
    }
    int lane = tid & 63, wv = tid >> 6;
    if (lane == 0) { s_red[wv] = v0; s_red[4 + wv] = v1; }
    __syncthreads();
    if (tid == 0) {
        float a0 = 0.0f, a1 = 0.0f;
        for (int i = 0; i < 4; ++i) { a0 += s_red[i]; a1 += s_red[4 + i]; }
        outp[0] = a0 + ((epoch[0] > 15) ? a1 : 0.0f);   // PRETRAIN=15
    }
}

} // namespace

extern "C" void kernel_launch(void* const* d_in, const int* in_sizes, int n_in,
                              void* d_out, int out_size, void* d_ws, size_t ws_size,
                              hipStream_t stream)
{
    const float* out_t = (const float*)d_in[0];
    const float* tgt   = (const float*)d_in[1];
    const int*   epoch = (const int*)d_in[2];
    float* loss = (float*)d_out;

    char* ws = (char*)d_ws;
    int*   tmap    = (int*)ws;                                   // N ints
    float* t_conf  = (float*)(ws + (size_t)N_ * sizeof(int));    // 1600
    float* t_txs   = t_conf + NB_ * NT_;                         // 1600*9
    float* t_tys   = t_txs + NB_ * NT_ * K_;                     // 1600*9
    int*   t_cls   = (int*)(t_tys + NB_ * NT_ * K_);             // 1600
    float* partial = (float*)(t_cls + NB_ * NT_);                // 640*2

    hipMemsetAsync(tmap, 0, (size_t)N_ * sizeof(int), stream);
    k_targets<<<(NB_ * NT_ + 255) / 256, 256, 0, stream>>>(
        out_t, tgt, tmap, t_conf, t_txs, t_tys, t_cls);
    k_cells<<<NB_ * SUBS, 256, 0, stream>>>(
        out_t, tgt, tmap, t_conf, t_txs, t_tys, t_cls, partial);
    k_final<<<1, 256, 0, stream>>>(partial, epoch, loss);
}

// Round 2
// 60.629 us; speedup vs baseline: 1.8704x; 1.8704x over previous
//
#include <hip/hip_runtime.h>
#include <math.h>

namespace {

constexpr int K_   = 9;
constexpr int NC_  = 13;
constexpr int NA_  = 5;
constexpr int NL_  = 21;      // 2K+3
constexpr int NB_  = 32;
constexpr int NH_  = 32;
constexpr int NW_  = 32;
constexpr int NPIX = NH_ * NW_;     // 1024
constexpr int M_   = NA_ * NPIX;    // 5120
constexpr int N_   = NB_ * M_;      // 163840
constexpr int NT_  = 50;
constexpr int CH_  = 2 * K_ + 1 + NC_;  // 32 channels per anchor
constexpr int SUBS = M_ / 256;      // 20 blocks per batch in k_cells

constexpr float TH_    = 30.0f;
constexpr float SHARP_ = 2.0f;
constexpr float IMW_   = 640.0f;
constexpr float IMH_   = 480.0f;
constexpr float EPS_   = 1e-5f;
constexpr float SIL_   = 0.6f;
constexpr float OBJ_   = 5.0f;

constexpr float L2E_ = 1.4426950408889634f;
constexpr float CC1_ = -(SHARP_ / TH_) * L2E_;   // slope in log2 domain
constexpr float CC2_ = SHARP_ * L2E_;            // offset in log2 domain

__device__ __constant__ float c_aw[5] = {1.482f, 2.0501f, 2.3946f, 3.1018f, 3.4879f};
__device__ __constant__ float c_ah[5] = {2.2412f, 3.1265f, 4.6891f, 3.991f, 5.2505f};

__device__ __forceinline__ float sigm(float x) { return 1.0f / (1.0f + expf(-x)); }

// corner-conf term in exp2 domain: exp(SHARP*(1-d/TH)) - 1, masked to d<TH
__device__ __forceinline__ float conf_term(float d2) {
    float arg = fmaf(__builtin_amdgcn_sqrtf(d2), CC1_, CC2_);
    float e = __builtin_amdgcn_exp2f(arg) - 1.0f;
    return (d2 < TH_ * TH_) ? e : 0.0f;
}

// ---------------- Kernel 1: per-target bookkeeping (1600 targets) -------------
__global__ void k_targets(const float* __restrict__ outp,
                          const float* __restrict__ tgt,
                          int*   __restrict__ tmap,
                          float* __restrict__ t_conf,
                          float* __restrict__ t_txs,
                          float* __restrict__ t_tys,
                          int*   __restrict__ t_cls)
{
    int idx = blockIdx.x * blockDim.x + threadIdx.x;
    if (idx >= NB_ * NT_) return;
    int b = idx / NT_, t = idx - b * NT_;
    const float* tb  = tgt + (size_t)b * NT_ * NL_;
    const float* row = tb + t * NL_;

    // valid = cumprod over t of (first-kp-x != 0)
    bool valid = true;
    for (int tp = 0; tp <= t; ++tp)
        if (tb[tp * NL_ + 1] == 0.0f) { valid = false; break; }

    float gxn[K_], gyn[K_];
#pragma unroll
    for (int k = 0; k < K_; ++k) { gxn[k] = row[1 + 2 * k]; gyn[k] = row[2 + 2 * k]; }

    int gi0 = (int)(gxn[0] * (float)NW_);
    int gj0 = (int)(gyn[0] * (float)NH_);
    float gw = row[NL_ - 2] * (float)NW_;
    float gh = row[NL_ - 1] * (float)NH_;

    // best anchor by IoU (first-max, -1 if max<=0)
    float best_iou = 0.0f; int best_n = -1;
#pragma unroll
    for (int a = 0; a < NA_; ++a) {
        float cw  = fminf(c_aw[a], gw);
        float chh = fminf(c_ah[a], gh);
        float iou = 0.0f;
        if (cw > 0.0f && chh > 0.0f) {
            float inter = cw * chh;
            iou = inter / (c_aw[a] * c_ah[a] + gw * gh - inter);
        }
        if (iou > best_iou) { best_iou = iou; best_n = a; }
    }
    int bn = ((best_n % NA_) + NA_) % NA_;   // Python -1 % 5 == 4
    int flat = ((b * NA_ + bn) * NH_ + gj0) * NW_ + gi0;

#pragma unroll
    for (int k = 0; k < K_; ++k) {
        t_txs[idx * K_ + k] = gxn[k] * (float)NW_ - (float)gi0;
        t_tys[idx * K_ + k] = gyn[k] * (float)NH_ - (float)gj0;
    }
    t_cls[idx] = (int)row[0];

    // conf_t: corner-conf against prediction at cell pb = (b*M - nPix + gj0*nW + gi0) mod N
    long long pbl = (long long)b * M_ - NPIX + gj0 * NW_ + gi0;
    int pb = (int)(((pbl % N_) + N_) % N_);
    int b2 = pb / M_;   int m2   = pb - b2 * M_;
    int a2 = m2 / NPIX; int pix2 = m2 - a2 * NPIX;
    int h2 = pix2 / NW_; int w2 = pix2 - h2 * NW_;
    const float* cb = outp + ((size_t)(b2 * NA_ + a2)) * CH_ * NPIX + pix2;

    float xsv[K_], ysv[K_];
    xsv[0] = sigm(cb[0]);
    ysv[0] = sigm(cb[NPIX]);
#pragma unroll
    for (int k = 1; k < K_; ++k) {
        xsv[k] = cb[(size_t)(k + 2) * NPIX];   // channels 3..10
        ysv[k] = cb[(size_t)(k + 3) * NPIX];   // channels 4..11 (overlap is intentional)
    }
    float s = 0.0f;
#pragma unroll
    for (int k = 0; k < K_; ++k) {
        float dx = fmaf(xsv[k] + (float)w2, IMW_ / NW_, -gxn[k] * IMW_);
        float dy = fmaf(ysv[k] + (float)h2, IMH_ / NH_, -gyn[k] * IMH_);
        float d2 = fmaf(dx, dx, dy * dy);
        s += conf_term(d2);
    }
    t_conf[idx] = s * (1.0f / ((expf(SHARP_) - 1.0f + EPS_) * (float)K_));

    if (valid) atomicMax(&tmap[flat], t + 1);   // scatter-max: order-independent
}

// ---------------- Kernel 2: per-cell losses (N cells) -------------------------
__global__ __launch_bounds__(256) void k_cells(
        const float* __restrict__ outp,
        const float* __restrict__ tgt,
        const int*   __restrict__ tmap,
        const float* __restrict__ t_conf,
        const float* __restrict__ t_txs,
        const float* __restrict__ t_tys,
        const int*   __restrict__ t_cls,
        float* __restrict__ partial)
{
    __shared__ float2 s_kp[NT_ * K_];   // {gx*IMW, gy*IMH} per (t,k)
    __shared__ int   s_nv;
    __shared__ float s_red[8];

    int b   = blockIdx.x / SUBS;
    int sub = blockIdx.x - b * SUBS;
    int tid = threadIdx.x;

    const float* tb = tgt + (size_t)b * NT_ * NL_;
    for (int i = tid; i < NT_ * K_; i += 256) {
        int t = i / K_, k = i - t * K_;
        s_kp[i] = make_float2(tb[t * NL_ + 1 + 2 * k] * IMW_,
                              tb[t * NL_ + 2 + 2 * k] * IMH_);
    }
    if (tid == 0) {
        int nv = 0;
        while (nv < NT_ && tb[nv * NL_ + 1] != 0.0f) nv++;
        s_nv = nv;
    }
    __syncthreads();

    int m = sub * 256 + tid;
    int n = b * M_ + m;
    int a = m / NPIX;  int pix = m - a * NPIX;
    int h = pix / NW_; int w   = pix - h * NW_;
    const float* cb = outp + ((size_t)(b * NA_ + a)) * CH_ * NPIX + pix;

    float xsv[K_], ysv[K_], pxs[K_], pys[K_];
    xsv[0] = sigm(cb[0]);
    ysv[0] = sigm(cb[NPIX]);
#pragma unroll
    for (int k = 1; k < K_; ++k) {
        xsv[k] = cb[(size_t)(k + 2) * NPIX];
        ysv[k] = cb[(size_t)(k + 3) * NPIX];
    }
#pragma unroll
    for (int k = 0; k < K_; ++k) {
        pxs[k] = (xsv[k] + (float)w) * (IMW_ / NW_);   // px * IMW
        pys[k] = (ysv[k] + (float)h) * (IMH_ / NH_);   // py * IMH
    }

    // cur = max over valid targets of sum-k corner conf (scale applied after max)
    int nv = s_nv;
    float cur = 0.0f;
    for (int t = 0; t < nv; ++t) {
        float s = 0.0f;
#pragma unroll
        for (int k = 0; k < K_; ++k) {
            float2 g = s_kp[t * K_ + k];
            float dx = g.x - pxs[k];
            float dy = g.y - pys[k];
            float d2 = fmaf(dx, dx, dy * dy);
            s += conf_term(d2);
        }
        cur = fmaxf(cur, s);
    }
    cur *= 1.0f / ((expf(SHARP_) - 1.0f + EPS_) * (float)K_);
    float cm0 = (cur > SIL_) ? 0.0f : 1.0f;    // NOOBJ=1

    int tm = tmap[n];
    float cf = sigm(cb[(size_t)(2 * K_) * NPIX]);   // channel 18
    float acc_main = 0.0f, acc_conf = 0.0f;
    if (tm > 0) {
        int widx = b * NT_ + (tm - 1);
        float lxy = 0.0f;
#pragma unroll
        for (int k = 0; k < K_; ++k) {
            float ddx = xsv[k] - t_txs[widx * K_ + k];
            float ddy = ysv[k] - t_tys[widx * K_ + k];
            lxy += ddx * ddx + ddy * ddy;
        }
        float diff = cf - t_conf[widx];
        acc_conf = 0.5f * OBJ_ * diff * diff;

        float logits[NC_]; float mx = -1e30f;
#pragma unroll
        for (int c = 0; c < NC_; ++c) {
            logits[c] = cb[(size_t)(2 * K_ + 1 + c) * NPIX];
            mx = fmaxf(mx, logits[c]);
        }
        float se = 0.0f;
#pragma unroll
        for (int c = 0; c < NC_; ++c) se += __builtin_amdgcn_exp2f((logits[c] - mx) * L2E_);
        int ci = t_cls[widx];
        ci = ci < 0 ? 0 : (ci > NC_ - 1 ? NC_ - 1 : ci);   // JAX gather clamps
        acc_main = 0.5f * lxy + (mx + logf(se) - logits[ci]);
    } else {
        acc_conf = 0.5f * cf * cf * cm0;
    }

    // deterministic block reduction
    float v0 = acc_main, v1 = acc_conf;
#pragma unroll
    for (int off = 32; off > 0; off >>= 1) {
        v0 += __shfl_down(v0, off);
        v1 += __shfl_down(v1, off);
    }
    int lane = tid & 63, wv = tid >> 6;
    if (lane == 0) { s_red[wv] = v0; s_red[4 + wv] = v1; }
    __syncthreads();
    if (tid == 0) {
        float a0 = 0.0f, a1 = 0.0f;
        for (int i = 0; i < 4; ++i) { a0 += s_red[i]; a1 += s_red[4 + i]; }
        partial[blockIdx.x * 2]     = a0;
        partial[blockIdx.x * 2 + 1] = a1;
    }
}

// ---------------- Kernel 3: final reduction + epoch gate ----------------------
__global__ __launch_bounds__(256) void k_final(const float* __restrict__ partial,
                                               const int* __restrict__ epoch,
                                               float* __restrict__ outp)
{
    __shared__ float s_red[8];
    int tid = threadIdx.x;
    float v0 = 0.0f, v1 = 0.0f;
    for (int i = tid; i < NB_ * SUBS; i += 256) {
        v0 += partial[2 * i];
        v1 += partial[2 * i + 1];
    }
#pragma unroll
    for (int off = 32; off > 0; off >>= 1) {
        v0 += __shfl_down(v0, off);
        v1 += __shfl_down(v1, off);
    }
    int lane = tid & 63, wv = tid >> 6;
    if (lane == 0) { s_red[wv] = v0; s_red[4 + wv] = v1; }
    __syncthreads();
    if (tid == 0) {
        float a0 = 0.0f, a1 = 0.0f;
        for (int i = 0; i < 4; ++i) { a0 += s_red[i]; a1 += s_red[4 + i]; }
        outp[0] = a0 + ((epoch[0] > 15) ? a1 : 0.0f);   // PRETRAIN=15
    }
}

} // namespace

extern "C" void kernel_launch(void* const* d_in, const int* in_sizes, int n_in,
                              void* d_out, int out_size, void* d_ws, size_t ws_size,
                              hipStream_t stream)
{
    const float* out_t = (const float*)d_in[0];
    const float* tgt   = (const float*)d_in[1];
    const int*   epoch = (const int*)d_in[2];
    float* loss = (float*)d_out;

    char* ws = (char*)d_ws;
    int*   tmap    = (int*)ws;                                   // N ints
    float* t_conf  = (float*)(ws + (size_t)N_ * sizeof(int));    // 1600
    float* t_txs   = t_conf + NB_ * NT_;                         // 1600*9
    float* t_tys   = t_txs + NB_ * NT_ * K_;                     // 1600*9
    int*   t_cls   = (int*)(t_tys + NB_ * NT_ * K_);             // 1600
    float* partial = (float*)(t_cls + NB_ * NT_);                // 640*2

    hipMemsetAsync(tmap, 0, (size_t)N_ * sizeof(int), stream);
    k_targets<<<(NB_ * NT_ + 255) / 256, 256, 0, stream>>>(
        out_t, tgt, tmap, t_conf, t_txs, t_tys, t_cls);
    k_cells<<<NB_ * SUBS, 256, 0, stream>>>(
        out_t, tgt, tmap, t_conf, t_txs, t_tys, t_cls, partial);
    k_final<<<1, 256, 0, stream>>>(partial, epoch, loss);
}

// Round 3
// 40.004 us; speedup vs baseline: 2.8348x; 1.5156x over previous
//
#include <hip/hip_runtime.h>
#include <math.h>

namespace {

constexpr int K_   = 9;
constexpr int NC_  = 13;
constexpr int NA_  = 5;
constexpr int NL_  = 21;      // 2K+3
constexpr int NB_  = 32;
constexpr int NH_  = 32;
constexpr int NW_  = 32;
constexpr int NPIX = NH_ * NW_;     // 1024
constexpr int M_   = NA_ * NPIX;    // 5120
constexpr int N_   = NB_ * M_;      // 163840
constexpr int NT_  = 50;
constexpr int CH_  = 2 * K_ + 1 + NC_;  // 32 channels per anchor
constexpr int BLK  = 128;
constexpr int SUBS = M_ / BLK;      // 40 blocks per batch in k_cells

constexpr float TH_    = 30.0f;
constexpr float SHARP_ = 2.0f;
constexpr float IMW_   = 640.0f;
constexpr float IMH_   = 480.0f;
constexpr float EPS_   = 1e-5f;
constexpr float OBJ_   = 5.0f;

constexpr float L2E_  = 1.4426950408889634f;
constexpr float CC1_  = -(SHARP_ / TH_) * L2E_;   // slope per pixel-distance, log2 domain
constexpr float CC2_  = SHARP_ * L2E_;            // offset, log2 domain
constexpr float CC1N_ = CC1_ * IMW_;              // slope per normalized-distance
constexpr float R2N_  = (TH_ / IMW_) * (TH_ / IMW_);  // (30/640)^2, exact: 9/4096
// SIL * ((e^2-1)+eps) * K  : sum-domain silence threshold
constexpr float SUMTHR_ = 34.500957f;

__device__ __constant__ float c_aw[5] = {1.482f, 2.0501f, 2.3946f, 3.1018f, 3.4879f};
__device__ __constant__ float c_ah[5] = {2.2412f, 3.1265f, 4.6891f, 3.991f, 5.2505f};

__device__ __forceinline__ float sigm(float x) {
    return 1.0f / (1.0f + __builtin_amdgcn_exp2f(-L2E_ * x));
}

// corner-conf term, pixel-domain d2: exp(SHARP*(1-d/TH)) - 1, masked to d<TH
__device__ __forceinline__ float conf_term_px(float d2) {
    float e = __builtin_amdgcn_exp2f(fmaf(__builtin_amdgcn_sqrtf(d2), CC1_, CC2_)) - 1.0f;
    return (d2 < TH_ * TH_) ? e : 0.0f;
}
// same in normalized domain (d2n = dx^2 + (0.75 dy)^2, x/y normalized)
__device__ __forceinline__ float conf_term_n(float d2n) {
    float e = __builtin_amdgcn_exp2f(fmaf(__builtin_amdgcn_sqrtf(d2n), CC1N_, CC2_)) - 1.0f;
    return (d2n < R2N_) ? e : 0.0f;
}

// ---------------- Kernel 1: per-target bookkeeping (1600 targets) -------------
__global__ void k_targets(const float* __restrict__ outp,
                          const float* __restrict__ tgt,
                          int*   __restrict__ t_flat,
                          float* __restrict__ t_conf,
                          float* __restrict__ t_txs,
                          float* __restrict__ t_tys,
                          int*   __restrict__ t_cls)
{
    int idx = blockIdx.x * blockDim.x + threadIdx.x;
    if (idx >= NB_ * NT_) return;
    int b = idx / NT_, t = idx - b * NT_;
    const float* tb  = tgt + (size_t)b * NT_ * NL_;
    const float* row = tb + t * NL_;

    // valid = cumprod over t of (first-kp-x != 0)
    bool valid = true;
    for (int tp = 0; tp <= t; ++tp)
        if (tb[tp * NL_ + 1] == 0.0f) { valid = false; break; }

    float gxn[K_], gyn[K_];
#pragma unroll
    for (int k = 0; k < K_; ++k) { gxn[k] = row[1 + 2 * k]; gyn[k] = row[2 + 2 * k]; }

    int gi0 = (int)(gxn[0] * (float)NW_);
    int gj0 = (int)(gyn[0] * (float)NH_);
    float gw = row[NL_ - 2] * (float)NW_;
    float gh = row[NL_ - 1] * (float)NH_;

    // best anchor by IoU (first-max, -1 if max<=0)
    float best_iou = 0.0f; int best_n = -1;
#pragma unroll
    for (int a = 0; a < NA_; ++a) {
        float cw  = fminf(c_aw[a], gw);
        float chh = fminf(c_ah[a], gh);
        float iou = 0.0f;
        if (cw > 0.0f && chh > 0.0f) {
            float inter = cw * chh;
            iou = inter / (c_aw[a] * c_ah[a] + gw * gh - inter);
        }
        if (iou > best_iou) { best_iou = iou; best_n = a; }
    }
    int bn = ((best_n % NA_) + NA_) % NA_;   // Python -1 % 5 == 4
    int flat = ((b * NA_ + bn) * NH_ + gj0) * NW_ + gi0;
    t_flat[idx] = valid ? flat : -1;

#pragma unroll
    for (int k = 0; k < K_; ++k) {
        t_txs[idx * K_ + k] = gxn[k] * (float)NW_ - (float)gi0;
        t_tys[idx * K_ + k] = gyn[k] * (float)NH_ - (float)gj0;
    }
    t_cls[idx] = (int)row[0];

    // conf_t: corner-conf against prediction at cell pb = (b*M - nPix + gj0*nW + gi0) mod N
    long long pbl = (long long)b * M_ - NPIX + gj0 * NW_ + gi0;
    int pb = (int)(((pbl % N_) + N_) % N_);
    int b2 = pb / M_;   int m2   = pb - b2 * M_;
    int a2 = m2 / NPIX; int pix2 = m2 - a2 * NPIX;
    int h2 = pix2 / NW_; int w2 = pix2 - h2 * NW_;
    const float* cb = outp + ((size_t)(b2 * NA_ + a2)) * CH_ * NPIX + pix2;

    float xsv[K_], ysv[K_];
    xsv[0] = sigm(cb[0]);
    ysv[0] = sigm(cb[NPIX]);
#pragma unroll
    for (int k = 1; k < K_; ++k) {
        xsv[k] = cb[(size_t)(k + 2) * NPIX];   // channels 3..10
        ysv[k] = cb[(size_t)(k + 3) * NPIX];   // channels 4..11 (overlap is intentional)
    }
    float s = 0.0f;
#pragma unroll
    for (int k = 0; k < K_; ++k) {
        float dx = fmaf(xsv[k] + (float)w2, IMW_ / NW_, -gxn[k] * IMW_);
        float dy = fmaf(ysv[k] + (float)h2, IMH_ / NH_, -gyn[k] * IMH_);
        float d2 = fmaf(dx, dx, dy * dy);
        s += conf_term_px(d2);
    }
    t_conf[idx] = s * (1.0f / ((7.38905609893065f - 1.0f + EPS_) * (float)K_));
}

// ---------------- Kernel 2: per-cell losses (N cells) -------------------------
__global__ __launch_bounds__(BLK) void k_cells(
        const float* __restrict__ outp,
        const float* __restrict__ tgt,
        const int*   __restrict__ t_flat,
        const float* __restrict__ t_conf,
        const float* __restrict__ t_txs,
        const float* __restrict__ t_tys,
        const int*   __restrict__ t_cls,
        float* __restrict__ partial)
{
    __shared__ float2 s_kp[NT_][10];   // {gx, 0.75*gy} normalized; stride 10 for 16B align
    __shared__ int   s_win[BLK];
    __shared__ int   s_nv;
    __shared__ float s_red[4];

    int b   = blockIdx.x / SUBS;
    int sub = blockIdx.x - b * SUBS;
    int tid = threadIdx.x;
    int base = b * M_ + sub * BLK;

    const float* tb = tgt + (size_t)b * NT_ * NL_;
    s_win[tid] = -1;
    for (int i = tid; i < NT_ * 10; i += BLK) {
        int t = i / 10, k = i - t * 10;
        if (k < 9)
            s_kp[t][k] = make_float2(tb[t * NL_ + 1 + 2 * k],
                                     0.75f * tb[t * NL_ + 2 + 2 * k]);
    }
    if (tid == 0) {
        int nv = 0;
        while (nv < NT_ && tb[nv * NL_ + 1] != 0.0f) nv++;
        s_nv = nv;
    }
    __syncthreads();
    if (tid < NT_) {
        int fl  = t_flat[b * NT_ + tid];
        int rel = fl - base;
        if (rel >= 0 && rel < BLK) atomicMax(&s_win[rel], tid);  // last(=max) t wins
    }
    __syncthreads();

    int m = sub * BLK + tid;
    int n = base + tid;
    int a = m / NPIX;  int pix = m - a * NPIX;
    int h = pix >> 5;  int w   = pix & 31;
    const float* cb = outp + ((size_t)(b * NA_ + a)) * CH_ * NPIX + pix;

    float xsv[K_], ysv[K_], qx[K_], qy[K_];
    xsv[0] = sigm(cb[0]);
    ysv[0] = sigm(cb[NPIX]);
#pragma unroll
    for (int k = 1; k < K_; ++k) {
        xsv[k] = cb[(size_t)(k + 2) * NPIX];
        ysv[k] = cb[(size_t)(k + 3) * NPIX];
    }
#pragma unroll
    for (int k = 0; k < K_; ++k) {
        qx[k] = (xsv[k] + (float)w) * (1.0f / NW_);          // px normalized
        qy[k] = (ysv[k] + (float)h) * (0.75f / NH_);         // 0.75 * py normalized
    }

    // ---- transcendental-free screen: a target can only push cur over SIL
    // ---- if >=6 of its 9 keypoints are within TH pixels.
    int anyflag = 0;
#pragma unroll 2
    for (int t = 0; t < NT_; ++t) {
        int cnt = 0;
#pragma unroll
        for (int k = 0; k < K_; ++k) {
            float2 g = s_kp[t][k];
            float dx = g.x - qx[k];
            float dy = g.y - qy[k];
            float d2 = fmaf(dx, dx, dy * dy);
            cnt += (d2 < R2N_) ? 1 : 0;
        }
        anyflag |= (cnt >= 6) ? 1 : 0;
    }
    float cm0 = 1.0f;                  // NOOBJ
    if (anyflag) {                     // exact fallback (rare; execz-skipped normally)
        float ms = 0.0f;
        int nv = s_nv;
        for (int t = 0; t < nv; ++t) {
            float s = 0.0f;
#pragma unroll
            for (int k = 0; k < K_; ++k) {
                float2 g = s_kp[t][k];
                float dx = g.x - qx[k];
                float dy = g.y - qy[k];
                s += conf_term_n(fmaf(dx, dx, dy * dy));
            }
            ms = fmaxf(ms, s);
        }
        cm0 = (ms > SUMTHR_) ? 0.0f : 1.0f;
    }

    int win = s_win[tid];
    float cf = sigm(cb[(size_t)(2 * K_) * NPIX]);   // channel 18
    float acc_main = 0.0f, acc_conf = 0.0f;
    if (win >= 0) {
        int widx = b * NT_ + win;
        float lxy = 0.0f;
#pragma unroll
        for (int k = 0; k < K_; ++k) {
            float ddx = xsv[k] - t_txs[widx * K_ + k];
            float ddy = ysv[k] - t_tys[widx * K_ + k];
            lxy += ddx * ddx + ddy * ddy;
        }
        float diff = cf - t_conf[widx];
        acc_conf = 0.5f * OBJ_ * diff * diff;

        float logits[NC_]; float mx = -1e30f;
#pragma unroll
        for (int c = 0; c < NC_; ++c) {
            logits[c] = cb[(size_t)(2 * K_ + 1 + c) * NPIX];
            mx = fmaxf(mx, logits[c]);
        }
        float se = 0.0f;
#pragma unroll
        for (int c = 0; c < NC_; ++c) se += __builtin_amdgcn_exp2f((logits[c] - mx) * L2E_);
        int ci = t_cls[widx];
        ci = ci < 0 ? 0 : (ci > NC_ - 1 ? NC_ - 1 : ci);   // JAX gather clamps
        acc_main = 0.5f * lxy + (mx + logf(se) - logits[ci]);
    } else {
        acc_conf = 0.5f * cf * cf * cm0;
    }

    // deterministic block reduction (2 waves)
    float v0 = acc_main, v1 = acc_conf;
#pragma unroll
    for (int off = 32; off > 0; off >>= 1) {
        v0 += __shfl_down(v0, off);
        v1 += __shfl_down(v1, off);
    }
    int lane = tid & 63, wv = tid >> 6;
    if (lane == 0) { s_red[wv] = v0; s_red[2 + wv] = v1; }
    __syncthreads();
    if (tid == 0) {
        partial[blockIdx.x * 2]     = s_red[0] + s_red[1];
        partial[blockIdx.x * 2 + 1] = s_red[2] + s_red[3];
    }
}

// ---------------- Kernel 3: final reduction + epoch gate ----------------------
__global__ __launch_bounds__(256) void k_final(const float* __restrict__ partial,
                                               const int* __restrict__ epoch,
                                               float* __restrict__ outp)
{
    __shared__ float s_red[8];
    int tid = threadIdx.x;
    float v0 = 0.0f, v1 = 0.0f;
    for (int i = tid; i < NB_ * SUBS; i += 256) {
        v0 += partial[2 * i];
        v1 += partial[2 * i + 1];
    }
#pragma unroll
    for (int off = 32; off > 0; off >>= 1) {
        v0 += __shfl_down(v0, off);
        v1 += __shfl_down(v1, off);
    }
    int lane = tid & 63, wv = tid >> 6;
    if (lane == 0) { s_red[wv] = v0; s_red[4 + wv] = v1; }
    __syncthreads();
    if (tid == 0) {
        float a0 = 0.0f, a1 = 0.0f;
        for (int i = 0; i < 4; ++i) { a0 += s_red[i]; a1 += s_red[4 + i]; }
        outp[0] = a0 + ((epoch[0] > 15) ? a1 : 0.0f);   // PRETRAIN=15
    }
}

} // namespace

extern "C" void kernel_launch(void* const* d_in, const int* in_sizes, int n_in,
                              void* d_out, int out_size, void* d_ws, size_t ws_size,
                              hipStream_t stream)
{
    const float* out_t = (const float*)d_in[0];
    const float* tgt   = (const float*)d_in[1];
    const int*   epoch = (const int*)d_in[2];
    float* loss = (float*)d_out;

    char* ws = (char*)d_ws;
    int*   t_flat  = (int*)ws;                                   // 1600
    float* t_conf  = (float*)(t_flat + NB_ * NT_);               // 1600
    float* t_txs   = t_conf + NB_ * NT_;                         // 1600*9
    float* t_tys   = t_txs + NB_ * NT_ * K_;                     // 1600*9
    int*   t_cls   = (int*)(t_tys + NB_ * NT_ * K_);             // 1600
    float* partial = (float*)(t_cls + NB_ * NT_);                // 1280*2

    k_targets<<<(NB_ * NT_ + 255) / 256, 256, 0, stream>>>(
        out_t, tgt, t_flat, t_conf, t_txs, t_tys, t_cls);
    k_cells<<<NB_ * SUBS, BLK, 0, stream>>>(
        out_t, tgt, t_flat, t_conf, t_txs, t_tys, t_cls, partial);
    k_final<<<1, 256, 0, stream>>>(partial, epoch, loss);
}

// Round 4
// 24.486 us; speedup vs baseline: 4.6313x; 1.6337x over previous
//
#include <hip/hip_runtime.h>
#include <math.h>

namespace {

constexpr int K_   = 9;
constexpr int NC_  = 13;
constexpr int NA_  = 5;
constexpr int NL_  = 21;      // 2K+3
constexpr int NB_  = 32;
constexpr int NH_  = 32;
constexpr int NW_  = 32;
constexpr int NPIX = NH_ * NW_;     // 1024
constexpr int M_   = NA_ * NPIX;    // 5120
constexpr int N_   = NB_ * M_;      // 163840
constexpr int NT_  = 50;
constexpr int CH_  = 2 * K_ + 1 + NC_;  // 32 channels per anchor
constexpr int BLK  = 256;
constexpr int SUBS = M_ / BLK;      // 20 blocks per batch
constexpr int G_   = 4;             // target groups in k_screen

constexpr float TH_    = 30.0f;
constexpr float SHARP_ = 2.0f;
constexpr float IMW_   = 640.0f;
constexpr float IMH_   = 480.0f;
constexpr float EPS_   = 1e-5f;
constexpr float OBJ_   = 5.0f;

constexpr float L2E_  = 1.4426950408889634f;
constexpr float CC1_  = -(SHARP_ / TH_) * L2E_;   // slope per pixel-distance, log2 domain
constexpr float CC2_  = SHARP_ * L2E_;            // offset, log2 domain
// 0.6 * ((e^2-1)+eps) * 9 : sum-domain silence threshold
constexpr float SUMTHR_ = 34.500957f;

__device__ __constant__ float c_aw[5] = {1.482f, 2.0501f, 2.3946f, 3.1018f, 3.4879f};
__device__ __constant__ float c_ah[5] = {2.2412f, 3.1265f, 4.6891f, 3.991f, 5.2505f};

__device__ __forceinline__ float sigm(float x) {
    return 1.0f / (1.0f + __builtin_amdgcn_exp2f(-L2E_ * x));
}

// corner-conf term, pixel-domain d2: exp(SHARP*(1-d/TH)) - 1, masked to d<TH
__device__ __forceinline__ float conf_term_px(float d2) {
    float e = __builtin_amdgcn_exp2f(fmaf(__builtin_amdgcn_sqrtf(d2), CC1_, CC2_)) - 1.0f;
    return (d2 < TH_ * TH_) ? e : 0.0f;
}

// ---------------- Kernel 1: per-target bookkeeping (32 blocks x 1 wave) -------
__global__ __launch_bounds__(64) void k_targets(
        const float* __restrict__ outp,
        const float* __restrict__ tgt,
        int*   __restrict__ t_flat,
        float* __restrict__ t_conf,
        float* __restrict__ t_txs,
        float* __restrict__ t_tys,
        int*   __restrict__ t_cls,
        int*   __restrict__ d_nv)
{
    int b = blockIdx.x;
    int lane = threadIdx.x;
    const float* tb = tgt + (size_t)b * NT_ * NL_;

    float x0 = (lane < NT_) ? tb[lane * NL_ + 1] : 0.0f;
    unsigned long long mk = __ballot(lane < NT_ && x0 != 0.0f);
    int nv = (int)__builtin_ctzll((~mk) | (1ull << NT_));   // prefix length
    if (lane == 0) d_nv[b] = nv;
    if (lane >= NT_) return;

    int t = lane;
    int idx = b * NT_ + t;
    bool valid = t < nv;
    const float* row = tb + t * NL_;

    float gxn[K_], gyn[K_];
#pragma unroll
    for (int k = 0; k < K_; ++k) { gxn[k] = row[1 + 2 * k]; gyn[k] = row[2 + 2 * k]; }

    int gi0 = (int)(gxn[0] * (float)NW_);
    int gj0 = (int)(gyn[0] * (float)NH_);
    float gw = row[NL_ - 2] * (float)NW_;
    float gh = row[NL_ - 1] * (float)NH_;

    float best_iou = 0.0f; int best_n = -1;
#pragma unroll
    for (int a = 0; a < NA_; ++a) {
        float cw  = fminf(c_aw[a], gw);
        float chh = fminf(c_ah[a], gh);
        float iou = 0.0f;
        if (cw > 0.0f && chh > 0.0f) {
            float inter = cw * chh;
            iou = inter / (c_aw[a] * c_ah[a] + gw * gh - inter);
        }
        if (iou > best_iou) { best_iou = iou; best_n = a; }
    }
    int bn = ((best_n % NA_) + NA_) % NA_;   // Python -1 % 5 == 4
    int flat = ((b * NA_ + bn) * NH_ + gj0) * NW_ + gi0;
    t_flat[idx] = valid ? flat : -1;

#pragma unroll
    for (int k = 0; k < K_; ++k) {
        t_txs[idx * K_ + k] = gxn[k] * (float)NW_ - (float)gi0;
        t_tys[idx * K_ + k] = gyn[k] * (float)NH_ - (float)gj0;
    }
    t_cls[idx] = (int)row[0];

    // conf_t against prediction at cell pb = (b*M - nPix + gj0*nW + gi0) mod N
    long long pbl = (long long)b * M_ - NPIX + gj0 * NW_ + gi0;
    int pb = (int)(((pbl % N_) + N_) % N_);
    int b2 = pb / M_;   int m2   = pb - b2 * M_;
    int a2 = m2 / NPIX; int pix2 = m2 - a2 * NPIX;
    int h2 = pix2 / NW_; int w2 = pix2 - h2 * NW_;
    const float* cb = outp + ((size_t)(b2 * NA_ + a2)) * CH_ * NPIX + pix2;

    float xsv[K_], ysv[K_];
    xsv[0] = sigm(cb[0]);
    ysv[0] = sigm(cb[NPIX]);
#pragma unroll
    for (int k = 1; k < K_; ++k) {
        xsv[k] = cb[(size_t)(k + 2) * NPIX];
        ysv[k] = cb[(size_t)(k + 3) * NPIX];
    }
    float s = 0.0f;
#pragma unroll
    for (int k = 0; k < K_; ++k) {
        float dx = fmaf(xsv[k] + (float)w2, IMW_ / NW_, -gxn[k] * IMW_);
        float dy = fmaf(ysv[k] + (float)h2, IMH_ / NH_, -gyn[k] * IMH_);
        s += conf_term_px(fmaf(dx, dx, dy * dy));
    }
    t_conf[idx] = s * (1.0f / ((7.38905609893065f - 1.0f + EPS_) * 9.0f));
}

// ---------------- Kernel 2: silence screen (cells x 4 target-groups) ----------
__global__ __launch_bounds__(BLK) void k_screen(
        const float* __restrict__ outp,
        const float* __restrict__ tgt,
        unsigned char* __restrict__ flags)
{
    __shared__ float2 s_g[13][10];   // {gx_px, gy_px}; padded row

    int bx = blockIdx.x;
    int g  = bx / (NB_ * SUBS);      // group SLOWEST: same cells -> same XCD
    int r  = bx - g * (NB_ * SUBS);
    int b  = r / SUBS, sub = r - b * SUBS;
    int tid = threadIdx.x;
    int tstart = g * 13 - (g == 3 ? 1 : 0);     // 0,13,26,38
    int tcnt   = (g < 2) ? 13 : 12;

    const float* tb = tgt + (size_t)b * NT_ * NL_;
    if (tid < tcnt * 9) {
        int t = tid / 9, k = tid - t * 9;
        s_g[t][k] = make_float2(tb[(tstart + t) * NL_ + 1 + 2 * k] * IMW_,
                                tb[(tstart + t) * NL_ + 2 + 2 * k] * IMH_);
    }
    __syncthreads();

    int m = sub * BLK + tid;
    int a = m / NPIX; int pix = m - a * NPIX;
    int h = pix >> 5, w = pix & 31;
    const float* cb = outp + ((size_t)(b * NA_ + a)) * CH_ * NPIX + pix;

    float qy[K_];
    qy[0] = (sigm(cb[NPIX]) + (float)h) * (IMH_ / NH_);
#pragma unroll
    for (int k = 1; k < K_; ++k)
        qy[k] = (cb[(size_t)(k + 3) * NPIX] + (float)h) * (IMH_ / NH_);

    // y-only prescreen: cnt>=6 (2-D) implies ycnt>=6
    unsigned cand = 0;
    for (int t = 0; t < tcnt; ++t) {
        int yc = 0;
#pragma unroll
        for (int k = 0; k < K_; ++k) {
            float dy = s_g[t][k].y - qy[k];
            yc += (fabsf(dy) < TH_) ? 1 : 0;
        }
        cand |= (yc >= 6) ? (1u << t) : 0u;
    }

    int flag = 0;
    if (cand) {                     // rare: full 2-D count for candidate targets
        float qx[K_];
        qx[0] = (sigm(cb[0]) + (float)w) * (IMW_ / NW_);
#pragma unroll
        for (int k = 1; k < K_; ++k)
            qx[k] = (cb[(size_t)(k + 2) * NPIX] + (float)w) * (IMW_ / NW_);
        for (int t = 0; t < tcnt; ++t) {
            if ((cand >> t) & 1u) {
                int cnt = 0;
#pragma unroll
                for (int k = 0; k < K_; ++k) {
                    float dx = s_g[t][k].x - qx[k];
                    float dy = s_g[t][k].y - qy[k];
                    float d2 = fmaf(dx, dx, dy * dy);
                    cnt += (d2 < TH_ * TH_) ? 1 : 0;
                }
                flag |= (cnt >= 6) ? 1 : 0;
            }
        }
    }
    flags[(size_t)(b * M_ + m) * G_ + g] = (unsigned char)flag;
}

// ---------------- Kernel 3: per-cell losses -----------------------------------
__global__ __launch_bounds__(BLK) void k_cells(
        const float* __restrict__ outp,
        const float* __restrict__ tgt,
        const int*   __restrict__ t_flat,
        const float* __restrict__ t_conf,
        const float* __restrict__ t_txs,
        const float* __restrict__ t_tys,
        const int*   __restrict__ t_cls,
        const int*   __restrict__ d_nv,
        const unsigned int* __restrict__ flags4,
        float* __restrict__ partial)
{
    __shared__ int   s_win[BLK];
    __shared__ float s_red[8];

    int bx = blockIdx.x;
    int b = bx / SUBS, sub = bx - b * SUBS;
    int tid = threadIdx.x;
    int base = b * M_ + sub * BLK;

    s_win[tid] = -1;
    __syncthreads();
    if (tid < NT_) {
        int fl  = t_flat[b * NT_ + tid];
        int rel = fl - base;
        if (rel >= 0 && rel < BLK) atomicMax(&s_win[rel], tid);  // last(=max) t wins
    }
    __syncthreads();

    int m = sub * BLK + tid;
    int n = base + tid;
    int a = m / NPIX;  int pix = m - a * NPIX;
    int h = pix >> 5;  int w   = pix & 31;
    const float* cb = outp + ((size_t)(b * NA_ + a)) * CH_ * NPIX + pix;

    float cf = sigm(cb[(size_t)(2 * K_) * NPIX]);   // channel 18
    int win = s_win[tid];
    float acc_main = 0.0f, acc_conf = 0.0f;

    if (win >= 0) {
        int widx = b * NT_ + win;
        float xsv[K_], ysv[K_];
        xsv[0] = sigm(cb[0]);
        ysv[0] = sigm(cb[NPIX]);
#pragma unroll
        for (int k = 1; k < K_; ++k) {
            xsv[k] = cb[(size_t)(k + 2) * NPIX];
            ysv[k] = cb[(size_t)(k + 3) * NPIX];
        }
        float lxy = 0.0f;
#pragma unroll
        for (int k = 0; k < K_; ++k) {
            float ddx = xsv[k] - t_txs[widx * K_ + k];
            float ddy = ysv[k] - t_tys[widx * K_ + k];
            lxy += ddx * ddx + ddy * ddy;
        }
        float diff = cf - t_conf[widx];
        acc_conf = 0.5f * OBJ_ * diff * diff;

        float logits[NC_]; float mx = -1e30f;
#pragma unroll
        for (int c = 0; c < NC_; ++c) {
            logits[c] = cb[(size_t)(2 * K_ + 1 + c) * NPIX];
            mx = fmaxf(mx, logits[c]);
        }
        float se = 0.0f;
#pragma unroll
        for (int c = 0; c < NC_; ++c) se += __builtin_amdgcn_exp2f((logits[c] - mx) * L2E_);
        int ci = t_cls[widx];
        ci = ci < 0 ? 0 : (ci > NC_ - 1 ? NC_ - 1 : ci);   // JAX gather clamps
        acc_main = 0.5f * lxy + (mx + __builtin_amdgcn_logf(se) * (1.0f / L2E_) - logits[ci]);
    } else {
        float cm0 = 1.0f;
        if (flags4[n] != 0u) {       // rare exact fallback
            float qx[K_], qy[K_];
            qx[0] = (sigm(cb[0]) + (float)w) * (IMW_ / NW_);
            qy[0] = (sigm(cb[NPIX]) + (float)h) * (IMH_ / NH_);
#pragma unroll
            for (int k = 1; k < K_; ++k) {
                qx[k] = (cb[(size_t)(k + 2) * NPIX] + (float)w) * (IMW_ / NW_);
                qy[k] = (cb[(size_t)(k + 3) * NPIX] + (float)h) * (IMH_ / NH_);
            }
            const float* tb = tgt + (size_t)b * NT_ * NL_;
            int nv = d_nv[b];
            float ms = 0.0f;
            for (int t = 0; t < nv; ++t) {
                float s = 0.0f;
#pragma unroll
                for (int k = 0; k < K_; ++k) {
                    float dx = tb[t * NL_ + 1 + 2 * k] * IMW_ - qx[k];
                    float dy = tb[t * NL_ + 2 + 2 * k] * IMH_ - qy[k];
                    s += conf_term_px(fmaf(dx, dx, dy * dy));
                }
                ms = fmaxf(ms, s);
            }
            cm0 = (ms > SUMTHR_) ? 0.0f : 1.0f;
        }
        acc_conf = 0.5f * cf * cf * cm0;
    }

    // deterministic block reduction (4 waves)
    float v0 = acc_main, v1 = acc_conf;
#pragma unroll
    for (int off = 32; off > 0; off >>= 1) {
        v0 += __shfl_down(v0, off);
        v1 += __shfl_down(v1, off);
    }
    int lane = tid & 63, wv = tid >> 6;
    if (lane == 0) { s_red[wv] = v0; s_red[4 + wv] = v1; }
    __syncthreads();
    if (tid == 0) {
        float a0 = 0.0f, a1 = 0.0f;
        for (int i = 0; i < 4; ++i) { a0 += s_red[i]; a1 += s_red[4 + i]; }
        partial[bx * 2]     = a0;
        partial[bx * 2 + 1] = a1;
    }
}

// ---------------- Kernel 4: final reduction + epoch gate ----------------------
__global__ __launch_bounds__(256) void k_final(const float* __restrict__ partial,
                                               const int* __restrict__ epoch,
                                               float* __restrict__ outp)
{
    __shared__ float s_red[8];
    int tid = threadIdx.x;
    float v0 = 0.0f, v1 = 0.0f;
    for (int i = tid; i < NB_ * SUBS; i += 256) {
        v0 += partial[2 * i];
        v1 += partial[2 * i + 1];
    }
#pragma unroll
    for (int off = 32; off > 0; off >>= 1) {
        v0 += __shfl_down(v0, off);
        v1 += __shfl_down(v1, off);
    }
    int lane = tid & 63, wv = tid >> 6;
    if (lane == 0) { s_red[wv] = v0; s_red[4 + wv] = v1; }
    __syncthreads();
    if (tid == 0) {
        float a0 = 0.0f, a1 = 0.0f;
        for (int i = 0; i < 4; ++i) { a0 += s_red[i]; a1 += s_red[4 + i]; }
        outp[0] = a0 + ((epoch[0] > 15) ? a1 : 0.0f);   // PRETRAIN=15
    }
}

} // namespace

extern "C" void kernel_launch(void* const* d_in, const int* in_sizes, int n_in,
                              void* d_out, int out_size, void* d_ws, size_t ws_size,
                              hipStream_t stream)
{
    const float* out_t = (const float*)d_in[0];
    const float* tgt   = (const float*)d_in[1];
    const int*   epoch = (const int*)d_in[2];
    float* loss = (float*)d_out;

    char* ws = (char*)d_ws;
    int*   t_flat  = (int*)ws;                                   // 1600
    float* t_conf  = (float*)(t_flat + NB_ * NT_);               // 1600
    float* t_txs   = t_conf + NB_ * NT_;                         // 14400
    float* t_tys   = t_txs + NB_ * NT_ * K_;                     // 14400
    int*   t_cls   = (int*)(t_tys + NB_ * NT_ * K_);             // 1600
    int*   d_nv    = t_cls + NB_ * NT_;                          // 32
    unsigned char* flags = (unsigned char*)(d_nv + NB_);         // N*4 bytes
    float* partial = (float*)(flags + (size_t)N_ * G_);          // 1280

    k_targets<<<NB_, 64, 0, stream>>>(
        out_t, tgt, t_flat, t_conf, t_txs, t_tys, t_cls, d_nv);
    k_screen<<<G_ * NB_ * SUBS, BLK, 0, stream>>>(out_t, tgt, flags);
    k_cells<<<NB_ * SUBS, BLK, 0, stream>>>(
        out_t, tgt, t_flat, t_conf, t_txs, t_tys, t_cls, d_nv,
        (const unsigned int*)flags, partial);
    k_final<<<1, 256, 0, stream>>>(partial, epoch, loss);
}